// Round 10
// baseline (757.058 us; speedup 1.0000x reference)
//
#include <hip/hip_runtime.h>

// LIF scan: B=16, S=256, H=128, N=64. T = S*H = 32768 sequential steps per
// (b,n) chain; 1024 chains. Bit-exact with the numpy fp32 sequential
// reference (hard thresholds on rounded sums). Chain form (proven bit-exact
// R1..R8, absmax=0):
//     s' = prev ? x : fl(s + x);  prev' = s' > th
//
// R9 post-mortem: cross-BLOCK spin sync deadlocked (dispatch order is
// undefined; pass1 blocks not guaranteed resident before spinning pass2
// blocks -> G16 violation -> reset -> zero output). Fix: all producer/
// consumer synchronization INTRA-block (waves of a block are co-resident by
// definition), via LDS generation flags. No inter-block communication at all.
//
// R10 mega-block design (32 blocks = batch x neuron-half; 12 waves each):
//   wave 0 (chain):    32 chains; 4-deep pipelined ds_read_b128 of x from the
//                      x-ring; one ds_write_b128 of raw s per 4 steps into a
//                      4-slot s-ring; ~10 cyc/step dep-chain pace.
//   wave 1 (producer): global x rows -> x-ring, 2-row register pipeline
//                      (vmcnt wait is for a load issued ~2300 cyc earlier).
//   waves 2..11:       writers; consume s-ring rows, derive out/spike with
//                      the SAME s>th compare (bit-exact), write both tensors
//                      as contiguous 1 KB wave stores. Slot released after
//                      LDS reads complete -> global stores never drained.
// Ring safety via generation-numbered flags (monotone, poison-proof). One
// __syncthreads (flag init) executed uniformly by all 12 waves.

namespace {
constexpr int kB = 16;
constexpr int kS = 256;
constexpr int kH = 128;
constexpr int kN = 64;
constexpr int kT = kS * kH;                 // 32768
constexpr long kPerB = (long)kS * kN * kH;  // 2,097,152 per batch per tensor
constexpr int kWr = 10;                     // writer waves per block
}

typedef float v4f __attribute__((ext_vector_type(4)));

__device__ __forceinline__ int ld_flag(const int* p) {
  return __hip_atomic_load(p, __ATOMIC_RELAXED, __HIP_MEMORY_SCOPE_WORKGROUP);
}
__device__ __forceinline__ void st_flag(int* p, int v) {
  __hip_atomic_store(p, v, __ATOMIC_RELAXED, __HIP_MEMORY_SCOPE_WORKGROUP);
}
#define SPIN_UNTIL(ptr, want) \
  while (ld_flag(ptr) != (want)) __builtin_amdgcn_s_sleep(1)

__global__ __launch_bounds__(64 * (2 + kWr)) void lif_mega_kernel(
    const float* __restrict__ x, const float* __restrict__ thresh,
    const float* __restrict__ acc0, float* __restrict__ out) {
  const int bid = blockIdx.x;
  const int b = bid >> 1;        // batch
  const int half = bid & 1;      // neuron half
  const int n0 = half * 32;      // first neuron of this block
  const int tid = threadIdx.x;
  const int wid = tid >> 6;
  const int lane = tid & 63;
  const int l32 = lane & 31;

  // s-ring rows padded to 132 floats (528 B: 16B-aligned for b128; 4-way
  // bank aliasing on writes/reads — off the critical dep chain).
  __shared__ alignas(16) float sring[4][32][132];  // 66 KB
  __shared__ alignas(16) float xring[4][kH];       // 2 KB
  __shared__ float lth[kN];
  __shared__ int xflag[4], xrel[4], sflag[4], srel[4];

  if (tid < kN) lth[tid] = thresh[tid];
  if (tid < 4) {
    xflag[tid] = 0;          // producer sets t+1 when row t staged
    xrel[tid] = tid - 3;     // chain sets t+1 when row t consumed
    sflag[tid] = 0;          // chain sets t+1 when row t's s staged
    srel[tid] = tid - 3;     // writer sets t+1 when row t's s read out
  }
  __syncthreads();  // the ONLY barrier; executed uniformly by all 12 waves

  if (wid == 0) {
    // ======================= chain wave (the scan) =======================
    const float th = thresh[n0 + l32];
    float s = acc0[b * kN + n0 + l32];
    bool prev = false;

    // prime the 4-deep x read pipeline from row 0
    SPIN_UNTIL(&xflag[0], 1);
    v4f p0 = *(const v4f*)&xring[0][0];
    v4f p1 = *(const v4f*)&xring[0][4];
    v4f p2 = *(const v4f*)&xring[0][8];
    v4f p3 = *(const v4f*)&xring[0][12];

    for (int t = 0; t < kS; ++t) {
      if (t + 1 < kS) SPIN_UNTIL(&xflag[(t + 1) & 3], t + 2);  // for q>=28
      SPIN_UNTIL(&srel[t & 3], t - 3);  // s-ring slot free
      const float* bc = xring[t & 3];
      const float* bn = xring[(t + 1) & 3];
      float* sw = &sring[t & 3][l32][0];  // lanes 32..63 duplicate lanes 0..31

#pragma unroll
      for (int q = 0; q < 32; ++q) {
        v4f sq;
#pragma unroll
        for (int j = 0; j < 4; ++j) {
          const float xt = p0[j];
          const float u = s + xt;  // dep-chain op 1
          s = prev ? xt : u;       // dep-chain op 2
          prev = s > th;           // off-chain
          sq[j] = s;               // raw post-add value (pre-reset)
        }
        *(v4f*)(sw + q * 4) = sq;    // ds_write_b128, imm offset
        p0 = p1; p1 = p2; p2 = p3;   // rotation renames (unrolled)
        p3 = (q < 28) ? *(const v4f*)&bc[(q + 4) * 4]
                      : *(const v4f*)&bn[(q - 28) * 4];  // 16-step lookahead
      }
      asm volatile("s_waitcnt lgkmcnt(0)" ::: "memory");  // s data visible
      if (lane == 0) {
        st_flag(&sflag[t & 3], t + 1);  // publish row t to writers
        st_flag(&xrel[t & 3], t + 1);   // release x slot t
      }
    }
  } else if (wid == 1) {
    // ===================== producer wave (x staging) =====================
    const v4f* __restrict__ xg4 = (const v4f*)(x + (long)b * kT);
    v4f va = xg4[0 * 32 + l32];  // row 0 (per-lane addresses -> vector path)
    v4f vb = xg4[1 * 32 + l32];  // row 1
    for (int t = 0; t < kS; ++t) {
      SPIN_UNTIL(&xrel[t & 3], t - 3);  // slot free
      *(v4f*)&xring[t & 3][l32 * 4] = va;  // lanes 32..63 duplicate (merge)
      asm volatile("s_waitcnt lgkmcnt(0)" ::: "memory");
      if (lane == 0) st_flag(&xflag[t & 3], t + 1);
      va = vb;
      if (t + 2 < kS) vb = xg4[(t + 2) * 32 + l32];  // ~2-row lookahead
    }
  } else {
    // ======================== writer waves (10x) ========================
    const int w = wid - 2;
    const int hq = lane & 31;   // h quad index
    const int h0 = hq * 4;
    const int nh = lane >> 5;   // n parity within iteration
    float* __restrict__ obat = out + (long)b * kPerB;
    float* __restrict__ sbat = obat + (long)kB * kPerB;

    for (int t = w; t < kS; t += kWr) {
      SPIN_UNTIL(&sflag[t & 3], t + 1);
      const float(*sl)[132] = sring[t & 3];
      float* __restrict__ orow = obat + (long)t * (kN * kH);
      float* __restrict__ srow = sbat + (long)t * (kN * kH);
#pragma unroll
      for (int i = 0; i < 16; ++i) {
        const int nl = 2 * i + nh;  // 0..31 chain slot
        const v4f sv = *(const v4f*)&sl[nl][h0];  // ds_read_b128
        const float thn = lth[n0 + nl];           // broadcast LDS read
        v4f o, f;
#pragma unroll
        for (int j = 0; j < 4; ++j) {
          const bool sp = sv[j] > thn;  // same compare as the chain
          o[j] = sp ? sv[j] : 0.0f;
          f[j] = sp ? 1.0f : 0.0f;
        }
        const long off = (long)(n0 + nl) * kH + h0;
        *(v4f*)(orow + off) = o;  // lanes cover 1 KB contiguous
        *(v4f*)(srow + off) = f;  // lanes cover 1 KB contiguous
      }
      // release the slot as soon as the LDS reads are done; the global
      // stores keep draining in the background (never waited on).
      asm volatile("s_waitcnt lgkmcnt(0)" ::: "memory");
      if (lane == 0) st_flag(&srel[t & 3], t + 1);
    }
  }
}

// ---------------------------------------------------------------------------
extern "C" void kernel_launch(void* const* d_in, const int* in_sizes, int n_in,
                              void* d_out, int out_size, void* d_ws, size_t ws_size,
                              hipStream_t stream) {
  const float* inputs = (const float*)d_in[0];    // [B,S,H] fp32
  const float* threshes = (const float*)d_in[1];  // [N] fp32
  const float* acc0 = (const float*)d_in[2];      // [B,N] fp32
  float* out = (float*)d_out;

  // 32 blocks = 16 batches x 2 neuron-halves; 12 waves per block
  // (1 chain + 1 x-producer + 10 writers). All sync is intra-block LDS
  // generation flags -> no dispatch-order assumptions (G16-safe).
  lif_mega_kernel<<<kB * 2, 64 * (2 + kWr), 0, stream>>>(inputs, threshes,
                                                         acc0, out);
}